// Round 7
// baseline (54.067 us; speedup 1.0000x reference)
//
#include <hip/hip_runtime.h>
#include <hip/hip_fp16.h>
#include <cstdint>

#define BB 32
#define CC 256
#define HF 64
#define WF 64
#define MM 4096   // HF*WF
#define NN 64
#define MCHUNKS 16   // m-chunks per batch
#define MPB 256      // m per block (4 waves x 64)
#define KSTEPS 8     // 256 / 32
#define NBLK (BB * MCHUNKS)

typedef _Float16 half8 __attribute__((ext_vector_type(8)));
typedef __fp16 fp16x2 __attribute__((ext_vector_type(2)));
typedef float f32x4 __attribute__((ext_vector_type(4)));

// ws layout:
//   wq    : _Float16[BB * 16384]        fragment-linear q-hat     (1 MB)
//   partM : float[BB*NN][MCHUNKS]       per-(p,chunk) max         (128 KB)
//   partS : float[BB*NN][MCHUNKS]       per-(p,chunk) sumexp      (128 KB)
//   trgl  : float[BB*NN]
//   tidx  : int[BB*NN]
//   minfo : [0]=count(float), [1]=layout(int)

// ---------------- phase 0: gather + l2-normalize queries ----------------
__global__ void phase0_gather_norm(const float* __restrict__ fs,
                                   const float* __restrict__ kps_src,
                                   const float* __restrict__ kps_trg,
                                   const void* __restrict__ maskp,
                                   _Float16* __restrict__ wq,
                                   int* __restrict__ trgidx,
                                   float* __restrict__ minfoF,
                                   int* __restrict__ minfoI,
                                   float* __restrict__ out) {
  int blk = blockIdx.x;          // b*N + n
  int b = blk >> 6, n = blk & 63;
  int c = threadIdx.x;

  float kx = kps_src[blk * 2 + 0];
  float ky = kps_src[blk * 2 + 1];
  int fx = min(max((int)(kx * (1.0f / 16.0f)), 0), WF - 1);
  int fy = min(max((int)(ky * (1.0f / 16.0f)), 0), HF - 1);
  int pix = fy * WF + fx;

  float x = fs[((size_t)b * CC + c) * MM + pix];

  float v = x * x;
  #pragma unroll
  for (int off = 32; off >= 1; off >>= 1) v += __shfl_xor(v, off);
  __shared__ float ssum[4];
  int wid = c >> 6, lane = c & 63;
  if (lane == 0) ssum[wid] = v;
  __syncthreads();
  float tot = ssum[0] + ssum[1] + ssum[2] + ssum[3];
  float inv = 1.0f / fmaxf(sqrtf(tot), 1e-12f);

  // fragment-linear layout: lane l holds frag[16-dim=l&15][k=(l>>4)*8+j]
  int ks = c >> 5, kg = (c >> 3) & 3, j = c & 7;
  int nt = n >> 4, nr = n & 15;
  int lane_f = kg * 16 + nr;
  size_t off = (size_t)b * 16384 + (size_t)((ks * 4 + nt) * 64 + lane_f) * 8 + j;
  wq[off] = (_Float16)(x * inv);

  if (c == 0) {
    float tx = kps_trg[blk * 2 + 0], ty = kps_trg[blk * 2 + 1];
    int gx = min(max((int)(tx * (1.0f / 16.0f)), 0), WF - 1);
    int gy = min(max((int)(ty * (1.0f / 16.0f)), 0), HF - 1);
    trgidx[blk] = gy * WF + gx;
  }

  // ---- block 0 extra: mask layout detection + count + zero out ----
  if (blk == 0) {
    __shared__ int flagF, flagB;
    if (c == 0) { flagF = 0; flagB = 0; out[0] = 0.0f; }
    __syncthreads();
    const unsigned char* mb = (const unsigned char*)maskp;
    int lf = 0, lb = 0;
    for (int i = c; i < BB * NN; i += 256) {
      unsigned char vch = mb[i];
      int r = i & 3;
      if (r == 3 && vch == 0x3F) lf = 1;   // float32 1.0f pattern
      if (r != 0 && vch != 0) lb = 1;      // nonzero off-word byte
    }
    if (lf) atomicOr(&flagF, 1);
    if (lb) atomicOr(&flagB, 1);
    __syncthreads();
    int layout = flagF ? 2 : (flagB ? 0 : 1);  // 2=float32, 0=uchar, 1=int32

    float lc = 0.f;
    for (int i = c; i < BB * NN; i += 256) {
      float mval;
      if (layout == 2) mval = ((const float*)maskp)[i];
      else if (layout == 0) mval = (float)mb[i];
      else mval = (float)((const int*)maskp)[i];
      lc += mval;
    }
    #pragma unroll
    for (int o2 = 32; o2 >= 1; o2 >>= 1) lc += __shfl_xor(lc, o2);
    __shared__ float cs[4];
    if (lane == 0) cs[wid] = lc;
    __syncthreads();
    if (c == 0) {
      minfoF[0] = cs[0] + cs[1] + cs[2] + cs[3];
      minfoI[1] = layout;
    }
  }
}

// ------- phase B: MFMA logits + per-chunk softmax partials -------------
// Each wave: 64 m (4 float4-fragments jj, m = m0w + 16g + 4r + jj), 64 n.
__global__ void __launch_bounds__(256)
phaseB(const float* __restrict__ ft,
       const _Float16* __restrict__ wq,
       const int* __restrict__ tidx,
       float* __restrict__ partM,
       float* __restrict__ partS,
       float* __restrict__ trgl) {
  __shared__ _Float16 qf[16384];     // 32 KB: q-hat fragments for this b
  __shared__ int trg_lds[NN];
  __shared__ float pM[4 * NN], pS[4 * NN];

  int b = blockIdx.x >> 4, mc = blockIdx.x & 15;
  int tid = threadIdx.x;

  const uint4* src = (const uint4*)(wq + (size_t)b * 16384);
  uint4* dst = (uint4*)qf;
  #pragma unroll
  for (int i = 0; i < 8; ++i) dst[tid + 256 * i] = src[tid + 256 * i];
  if (tid < NN) trg_lds[tid] = tidx[b * NN + tid];
  __syncthreads();

  int w = tid >> 6, lane = tid & 63, g = lane >> 4, col = lane & 15;
  int m0w = mc * MPB + w * 64;       // this wave's first m (64-span)
  const float* fb = ft + (size_t)b * CC * MM;
  // lane loads float4 at [c = g*8 + j][m0w + 4*col]
  const float4* lb = (const float4*)(fb + (size_t)(g * 8) * MM + (m0w + 4 * col));
  // float4 index stride between c rows: MM/4
  #define ROW4 (MM / 4)

  f32x4 acc[4][4];   // [jj][nt]
  #pragma unroll
  for (int jj = 0; jj < 4; ++jj)
    #pragma unroll
    for (int nt = 0; nt < 4; ++nt) acc[jj][nt] = (f32x4){0.f, 0.f, 0.f, 0.f};
  float ssq[4] = {0.f, 0.f, 0.f, 0.f};

  const half8* qv = (const half8*)qf;

  float4 cur[8], nxt[8];
  #pragma unroll
  for (int j = 0; j < 8; ++j) cur[j] = lb[(size_t)j * ROW4];

  #pragma unroll
  for (int ks = 0; ks < KSTEPS; ++ks) {
    if (ks + 1 < KSTEPS) {
      #pragma unroll
      for (int j = 0; j < 8; ++j)
        nxt[j] = lb[(size_t)((ks + 1) * 32 + j) * ROW4];
    }

    half8 qn0 = qv[(ks * 4 + 0) * 64 + lane];
    half8 qn1 = qv[(ks * 4 + 1) * 64 + lane];
    half8 qn2 = qv[(ks * 4 + 2) * 64 + lane];
    half8 qn3 = qv[(ks * 4 + 3) * 64 + lane];

    // build 4 A-fragments (jj = m mod 4), element j = c-slot
    half8 aft[4];
    #pragma unroll
    for (int jj = 0; jj < 4; ++jj) {
      #pragma unroll
      for (int j = 0; j < 8; j += 2) {
        float u0 = cur[j][jj], u1 = cur[j + 1][jj];
        ssq[jj] += u0 * u0 + u1 * u1;
        fp16x2 h = __builtin_amdgcn_cvt_pkrtz(u0, u1);
        aft[jj][j] = (_Float16)h[0];
        aft[jj][j + 1] = (_Float16)h[1];
      }
    }

    #pragma unroll
    for (int jj = 0; jj < 4; ++jj) {
      acc[jj][0] = __builtin_amdgcn_mfma_f32_16x16x32_f16(aft[jj], qn0, acc[jj][0], 0, 0, 0);
      acc[jj][1] = __builtin_amdgcn_mfma_f32_16x16x32_f16(aft[jj], qn1, acc[jj][1], 0, 0, 0);
      acc[jj][2] = __builtin_amdgcn_mfma_f32_16x16x32_f16(aft[jj], qn2, acc[jj][2], 0, 0, 0);
      acc[jj][3] = __builtin_amdgcn_mfma_f32_16x16x32_f16(aft[jj], qn3, acc[jj][3], 0, 0, 0);
    }

    #pragma unroll
    for (int j = 0; j < 8; ++j) cur[j] = nxt[j];
  }

  // full column sumsq: lane's ssq[jj] covers c in group g; sum across groups
  #pragma unroll
  for (int jj = 0; jj < 4; ++jj) {
    ssq[jj] += __shfl_xor(ssq[jj], 16);
    ssq[jj] += __shfl_xor(ssq[jj], 32);
  }
  // output m = m0w + 16g + 4r + jj; its ssq lives at col' = 4g + r (any group)
  float sc[4][4];    // [jj][r]
  #pragma unroll
  for (int jj = 0; jj < 4; ++jj)
    #pragma unroll
    for (int r = 0; r < 4; ++r) {
      float t = __shfl(ssq[jj], 4 * g + r, 16);
      sc[jj][r] = 100.0f / fmaxf(sqrtf(t), 1e-12f);   // 1/(||f||*T)
    }

  #pragma unroll
  for (int nt = 0; nt < 4; ++nt) {
    int n = nt * 16 + col;           // this lane's n (fixed per lane)
    int t = trg_lds[n];
    float v[4][4];
    #pragma unroll
    for (int jj = 0; jj < 4; ++jj)
      #pragma unroll
      for (int r = 0; r < 4; ++r)
        v[jj][r] = acc[jj][nt][r] * sc[jj][r];

    #pragma unroll
    for (int jj = 0; jj < 4; ++jj)
      #pragma unroll
      for (int r = 0; r < 4; ++r)
        if (t == m0w + 16 * g + 4 * r + jj) trgl[b * NN + n] = v[jj][r];

    float mx = -1e30f;
    #pragma unroll
    for (int jj = 0; jj < 4; ++jj)
      #pragma unroll
      for (int r = 0; r < 4; ++r) mx = fmaxf(mx, v[jj][r]);
    mx = fmaxf(mx, __shfl_xor(mx, 16));
    mx = fmaxf(mx, __shfl_xor(mx, 32));
    float s = 0.f;
    #pragma unroll
    for (int jj = 0; jj < 4; ++jj)
      #pragma unroll
      for (int r = 0; r < 4; ++r) s += __expf(v[jj][r] - mx);
    s += __shfl_xor(s, 16);
    s += __shfl_xor(s, 32);
    if (g == 0) { pM[w * NN + n] = mx; pS[w * NN + n] = s; }
  }
  __syncthreads();

  if (tid < NN) {
    int n = tid;
    float gm = fmaxf(fmaxf(pM[n], pM[NN + n]), fmaxf(pM[2 * NN + n], pM[3 * NN + n]));
    float S = 0.f;
    #pragma unroll
    for (int ww = 0; ww < 4; ++ww)
      S += pS[ww * NN + n] * __expf(pM[ww * NN + n] - gm);
    // transposed layout: [p][chunk] for coalesced final reduce
    partM[(size_t)(b * NN + n) * MCHUNKS + mc] = gm;
    partS[(size_t)(b * NN + n) * MCHUNKS + mc] = S;
  }
}

// ---------------- final: lse merge + nll + masked mean ------------------
__global__ void __launch_bounds__(256)
reduceFinal(const float* __restrict__ partM,
            const float* __restrict__ partS,
            const float* __restrict__ trgl,
            const void* __restrict__ maskp,
            const float* __restrict__ minfoF,
            const int* __restrict__ minfoI,
            float* __restrict__ out) {
  int tid = threadIdx.x;
  int p = blockIdx.x * 256 + tid;    // 8 blocks x 256 = 2048 points

  const float4* pm4 = (const float4*)(partM + (size_t)p * MCHUNKS);
  const float4* ps4 = (const float4*)(partS + (size_t)p * MCHUNKS);
  float gm = -1e30f, S = 0.f;
  #pragma unroll
  for (int q = 0; q < MCHUNKS / 4; ++q) {
    float4 m4 = pm4[q];
    float4 s4 = ps4[q];
    #pragma unroll
    for (int e = 0; e < 4; ++e) {
      float mi = ((const float*)&m4)[e];
      float si = ((const float*)&s4)[e];
      float nm = fmaxf(gm, mi);
      S = S * __expf(gm - nm) + si * __expf(mi - nm);
      gm = nm;
    }
  }
  float nll = gm + logf(S) - trgl[p];

  int layout = minfoI[1];
  const unsigned char* mb = (const unsigned char*)maskp;
  float mval;
  if (layout == 2) mval = ((const float*)maskp)[p];
  else if (layout == 0) mval = (float)mb[p];
  else mval = (float)((const int*)maskp)[p];

  float v = nll * mval;
  #pragma unroll
  for (int off = 32; off >= 1; off >>= 1) v += __shfl_xor(v, off);
  __shared__ float ps[4];
  int w = tid >> 6, lane = tid & 63;
  if (lane == 0) ps[w] = v;
  __syncthreads();
  if (tid == 0) {
    float s = ps[0] + ps[1] + ps[2] + ps[3];
    float cnt = minfoF[0];
    atomicAdd(out, s / fmaxf(cnt, 1.0f));
  }
}

extern "C" void kernel_launch(void* const* d_in, const int* in_sizes, int n_in,
                              void* d_out, int out_size, void* d_ws, size_t ws_size,
                              hipStream_t stream) {
  const float* fs   = (const float*)d_in[0];
  const float* ft   = (const float*)d_in[1];
  const float* ksrc = (const float*)d_in[2];
  const float* ktrg = (const float*)d_in[3];
  const void*  mask = d_in[4];
  float* out = (float*)d_out;

  _Float16* wq = (_Float16*)d_ws;                        // BB*16384 halfs
  float* partM = (float*)((char*)d_ws + (size_t)BB * 16384 * 2);
  float* partS = partM + (size_t)BB * NN * MCHUNKS;
  float* trgl  = partS + (size_t)BB * NN * MCHUNKS;
  int* tidx    = (int*)(trgl + BB * NN);
  float* minfoF = (float*)(tidx + BB * NN);
  int* minfoI   = (int*)minfoF;

  phase0_gather_norm<<<BB * NN, 256, 0, stream>>>(fs, ksrc, ktrg, mask, wq, tidx,
                                                  minfoF, minfoI, out);
  phaseB<<<NBLK, 256, 0, stream>>>(ft, wq, tidx, partM, partS, trgl);
  reduceFinal<<<BB * NN / 256, 256, 0, stream>>>(partM, partS, trgl, mask,
                                                 minfoF, minfoI, out);
}

// Round 8
// 47.412 us; speedup vs baseline: 1.1404x; 1.1404x over previous
//
#include <hip/hip_runtime.h>
#include <hip/hip_fp16.h>
#include <cstdint>

#define BB 32
#define CC 256
#define HF 64
#define WF 64
#define MM 4096   // HF*WF
#define NN 64
#define MCHUNKS 32   // m-chunks per batch
#define MPB 128      // m per block (2 m-spans x 64)
#define KSTEPS 8     // 256 / 32
#define NBLK (BB * MCHUNKS)

typedef _Float16 half8 __attribute__((ext_vector_type(8)));
typedef __fp16 fp16x2 __attribute__((ext_vector_type(2)));
typedef float f32x4 __attribute__((ext_vector_type(4)));

// ws layout:
//   wq    : _Float16[BB * 16384]        fragment-linear q-hat     (1 MB)
//   partM : float[BB*NN][MCHUNKS]       per-(p,chunk) max         (256 KB)
//   partS : float[BB*NN][MCHUNKS]       per-(p,chunk) sumexp      (256 KB)
//   trgl  : float[BB*NN]
//   tidx  : int[BB*NN]
//   minfo : [0]=count(float), [1]=layout(int)

// ---------------- phase 0: gather + l2-normalize queries ----------------
__global__ void phase0_gather_norm(const float* __restrict__ fs,
                                   const float* __restrict__ kps_src,
                                   const float* __restrict__ kps_trg,
                                   const void* __restrict__ maskp,
                                   _Float16* __restrict__ wq,
                                   int* __restrict__ trgidx,
                                   float* __restrict__ minfoF,
                                   int* __restrict__ minfoI,
                                   float* __restrict__ out) {
  int blk = blockIdx.x;          // b*N + n
  int b = blk >> 6, n = blk & 63;
  int c = threadIdx.x;

  float kx = kps_src[blk * 2 + 0];
  float ky = kps_src[blk * 2 + 1];
  int fx = min(max((int)(kx * (1.0f / 16.0f)), 0), WF - 1);
  int fy = min(max((int)(ky * (1.0f / 16.0f)), 0), HF - 1);
  int pix = fy * WF + fx;

  float x = fs[((size_t)b * CC + c) * MM + pix];

  float v = x * x;
  #pragma unroll
  for (int off = 32; off >= 1; off >>= 1) v += __shfl_xor(v, off);
  __shared__ float ssum[4];
  int wid = c >> 6, lane = c & 63;
  if (lane == 0) ssum[wid] = v;
  __syncthreads();
  float tot = ssum[0] + ssum[1] + ssum[2] + ssum[3];
  float inv = 1.0f / fmaxf(sqrtf(tot), 1e-12f);

  // fragment-linear layout: lane l holds frag[16-dim=l&15][k=(l>>4)*8+j]
  int ks = c >> 5, kg = (c >> 3) & 3, j = c & 7;
  int nt = n >> 4, nr = n & 15;
  int lane_f = kg * 16 + nr;
  size_t off = (size_t)b * 16384 + (size_t)((ks * 4 + nt) * 64 + lane_f) * 8 + j;
  wq[off] = (_Float16)(x * inv);

  if (c == 0) {
    float tx = kps_trg[blk * 2 + 0], ty = kps_trg[blk * 2 + 1];
    int gx = min(max((int)(tx * (1.0f / 16.0f)), 0), WF - 1);
    int gy = min(max((int)(ty * (1.0f / 16.0f)), 0), HF - 1);
    trgidx[blk] = gy * WF + gx;
  }

  // ---- block 0 extra: mask layout detection + count + zero out ----
  if (blk == 0) {
    __shared__ int flagF, flagB;
    if (c == 0) { flagF = 0; flagB = 0; out[0] = 0.0f; }
    __syncthreads();
    const unsigned char* mb = (const unsigned char*)maskp;
    int lf = 0, lb = 0;
    for (int i = c; i < BB * NN; i += 256) {
      unsigned char vch = mb[i];
      int r = i & 3;
      if (r == 3 && vch == 0x3F) lf = 1;   // float32 1.0f pattern
      if (r != 0 && vch != 0) lb = 1;      // nonzero off-word byte
    }
    if (lf) atomicOr(&flagF, 1);
    if (lb) atomicOr(&flagB, 1);
    __syncthreads();
    int layout = flagF ? 2 : (flagB ? 0 : 1);  // 2=float32, 0=uchar, 1=int32

    float lc = 0.f;
    for (int i = c; i < BB * NN; i += 256) {
      float mval;
      if (layout == 2) mval = ((const float*)maskp)[i];
      else if (layout == 0) mval = (float)mb[i];
      else mval = (float)((const int*)maskp)[i];
      lc += mval;
    }
    #pragma unroll
    for (int o2 = 32; o2 >= 1; o2 >>= 1) lc += __shfl_xor(lc, o2);
    __shared__ float cs[4];
    if (lane == 0) cs[wid] = lc;
    __syncthreads();
    if (c == 0) {
      minfoF[0] = cs[0] + cs[1] + cs[2] + cs[3];
      minfoI[1] = layout;
    }
  }
}

// ------- phase B: MFMA logits + per-chunk softmax partials -------------
// Block: 128 m x 64 n. Wave (wm, wn): 64 m (jj-fragments) x 32 n (2 nt).
__global__ void __launch_bounds__(256, 4)
phaseB(const float* __restrict__ ft,
       const _Float16* __restrict__ wq,
       const int* __restrict__ tidx,
       float* __restrict__ partM,
       float* __restrict__ partS,
       float* __restrict__ trgl) {
  __shared__ _Float16 qf[16384];     // 32 KB: q-hat fragments for this b
  __shared__ int trg_lds[NN];
  __shared__ float pM[4 * NN], pS[4 * NN];

  int b = blockIdx.x >> 5, mc = blockIdx.x & 31;
  int tid = threadIdx.x;

  const uint4* src = (const uint4*)(wq + (size_t)b * 16384);
  uint4* dst = (uint4*)qf;
  #pragma unroll
  for (int i = 0; i < 8; ++i) dst[tid + 256 * i] = src[tid + 256 * i];
  if (tid < NN) trg_lds[tid] = tidx[b * NN + tid];
  __syncthreads();

  int w = tid >> 6, lane = tid & 63, g = lane >> 4, col = lane & 15;
  int wm = w & 1, wn = w >> 1;
  int m0w = mc * MPB + wm * 64;      // this wave's first m (64-span)
  const float* fb = ft + (size_t)b * CC * MM;
  // lane loads float4 at [c = g*8 + j][m0w + 4*col]
  const float4* lb = (const float4*)(fb + (size_t)(g * 8) * MM + (m0w + 4 * col));
  #define ROW4 (MM / 4)

  f32x4 acc[4][2];   // [jj][ntl]
  #pragma unroll
  for (int jj = 0; jj < 4; ++jj)
    #pragma unroll
    for (int ntl = 0; ntl < 2; ++ntl) acc[jj][ntl] = (f32x4){0.f, 0.f, 0.f, 0.f};
  float ssq[4] = {0.f, 0.f, 0.f, 0.f};

  const half8* qv = (const half8*)qf;

  #pragma unroll
  for (int ks = 0; ks < KSTEPS; ++ks) {
    float4 cur[8];
    #pragma unroll
    for (int j = 0; j < 8; ++j) cur[j] = lb[(size_t)(ks * 32 + j) * ROW4];

    // build 4 A-fragments (jj = m mod 4), element j = c-slot
    half8 aft[4];
    #pragma unroll
    for (int jj = 0; jj < 4; ++jj) {
      #pragma unroll
      for (int j = 0; j < 8; j += 2) {
        float u0 = cur[j][jj], u1 = cur[j + 1][jj];
        ssq[jj] += u0 * u0 + u1 * u1;
        fp16x2 h = __builtin_amdgcn_cvt_pkrtz(u0, u1);
        aft[jj][j] = (_Float16)h[0];
        aft[jj][j + 1] = (_Float16)h[1];
      }
    }

    #pragma unroll
    for (int ntl = 0; ntl < 2; ++ntl) {
      half8 qn = qv[(ks * 4 + (wn * 2 + ntl)) * 64 + lane];
      #pragma unroll
      for (int jj = 0; jj < 4; ++jj)
        acc[jj][ntl] = __builtin_amdgcn_mfma_f32_16x16x32_f16(aft[jj], qn, acc[jj][ntl], 0, 0, 0);
    }
  }

  // full column sumsq: lane's ssq[jj] covers c in group g; sum across groups
  #pragma unroll
  for (int jj = 0; jj < 4; ++jj) {
    ssq[jj] += __shfl_xor(ssq[jj], 16);
    ssq[jj] += __shfl_xor(ssq[jj], 32);
  }
  // output m = m0w + 16g + 4r + jj; its ssq lives at col' = 4g + r (any group)
  float sc[4][4];    // [jj][r]
  #pragma unroll
  for (int jj = 0; jj < 4; ++jj)
    #pragma unroll
    for (int r = 0; r < 4; ++r) {
      float t = __shfl(ssq[jj], 4 * g + r, 16);
      sc[jj][r] = 100.0f / fmaxf(sqrtf(t), 1e-12f);   // 1/(||f||*T)
    }

  #pragma unroll
  for (int ntl = 0; ntl < 2; ++ntl) {
    int nt2 = wn * 2 + ntl;
    int n = nt2 * 16 + col;          // this lane's n (fixed per lane)
    int t = trg_lds[n];
    float v[4][4];
    #pragma unroll
    for (int jj = 0; jj < 4; ++jj)
      #pragma unroll
      for (int r = 0; r < 4; ++r)
        v[jj][r] = acc[jj][ntl][r] * sc[jj][r];

    #pragma unroll
    for (int jj = 0; jj < 4; ++jj)
      #pragma unroll
      for (int r = 0; r < 4; ++r)
        if (t == m0w + 16 * g + 4 * r + jj) trgl[b * NN + n] = v[jj][r];

    float mx = -1e30f;
    #pragma unroll
    for (int jj = 0; jj < 4; ++jj)
      #pragma unroll
      for (int r = 0; r < 4; ++r) mx = fmaxf(mx, v[jj][r]);
    mx = fmaxf(mx, __shfl_xor(mx, 16));
    mx = fmaxf(mx, __shfl_xor(mx, 32));
    float s = 0.f;
    #pragma unroll
    for (int jj = 0; jj < 4; ++jj)
      #pragma unroll
      for (int r = 0; r < 4; ++r) s += __expf(v[jj][r] - mx);
    s += __shfl_xor(s, 16);
    s += __shfl_xor(s, 32);
    if (g == 0) { pM[w * NN + n] = mx; pS[w * NN + n] = s; }
  }
  __syncthreads();

  // combine the two m-span waves (w = 2h, 2h+1 where h = n>>5)
  if (tid < NN) {
    int n = tid;
    int h = n >> 5;
    float mA = pM[(2 * h + 0) * NN + n], mBv = pM[(2 * h + 1) * NN + n];
    float sA = pS[(2 * h + 0) * NN + n], sBv = pS[(2 * h + 1) * NN + n];
    float gm = fmaxf(mA, mBv);
    float S = sA * __expf(mA - gm) + sBv * __expf(mBv - gm);
    // transposed layout: [p][chunk] for coalesced final reduce
    partM[(size_t)(b * NN + n) * MCHUNKS + mc] = gm;
    partS[(size_t)(b * NN + n) * MCHUNKS + mc] = S;
  }
}

// ---------------- final: lse merge + nll + masked mean ------------------
__global__ void __launch_bounds__(256)
reduceFinal(const float* __restrict__ partM,
            const float* __restrict__ partS,
            const float* __restrict__ trgl,
            const void* __restrict__ maskp,
            const float* __restrict__ minfoF,
            const int* __restrict__ minfoI,
            float* __restrict__ out) {
  int tid = threadIdx.x;
  int p = blockIdx.x * 256 + tid;    // 8 blocks x 256 = 2048 points

  const float4* pm4 = (const float4*)(partM + (size_t)p * MCHUNKS);
  const float4* ps4 = (const float4*)(partS + (size_t)p * MCHUNKS);
  float gm = -1e30f, S = 0.f;
  #pragma unroll
  for (int q = 0; q < MCHUNKS / 4; ++q) {
    float4 m4 = pm4[q];
    float4 s4 = ps4[q];
    #pragma unroll
    for (int e = 0; e < 4; ++e) {
      float mi = ((const float*)&m4)[e];
      float si = ((const float*)&s4)[e];
      float nm = fmaxf(gm, mi);
      S = S * __expf(gm - nm) + si * __expf(mi - nm);
      gm = nm;
    }
  }
  float nll = gm + logf(S) - trgl[p];

  int layout = minfoI[1];
  const unsigned char* mb = (const unsigned char*)maskp;
  float mval;
  if (layout == 2) mval = ((const float*)maskp)[p];
  else if (layout == 0) mval = (float)mb[p];
  else mval = (float)((const int*)maskp)[p];

  float v = nll * mval;
  #pragma unroll
  for (int off = 32; off >= 1; off >>= 1) v += __shfl_xor(v, off);
  __shared__ float ps[4];
  int w = tid >> 6, lane = tid & 63;
  if (lane == 0) ps[w] = v;
  __syncthreads();
  if (tid == 0) {
    float s = ps[0] + ps[1] + ps[2] + ps[3];
    float cnt = minfoF[0];
    atomicAdd(out, s / fmaxf(cnt, 1.0f));
  }
}

extern "C" void kernel_launch(void* const* d_in, const int* in_sizes, int n_in,
                              void* d_out, int out_size, void* d_ws, size_t ws_size,
                              hipStream_t stream) {
  const float* fs   = (const float*)d_in[0];
  const float* ft   = (const float*)d_in[1];
  const float* ksrc = (const float*)d_in[2];
  const float* ktrg = (const float*)d_in[3];
  const void*  mask = d_in[4];
  float* out = (float*)d_out;

  _Float16* wq = (_Float16*)d_ws;                        // BB*16384 halfs
  float* partM = (float*)((char*)d_ws + (size_t)BB * 16384 * 2);
  float* partS = partM + (size_t)BB * NN * MCHUNKS;
  float* trgl  = partS + (size_t)BB * NN * MCHUNKS;
  int* tidx    = (int*)(trgl + BB * NN);
  float* minfoF = (float*)(tidx + BB * NN);
  int* minfoI   = (int*)minfoF;

  phase0_gather_norm<<<BB * NN, 256, 0, stream>>>(fs, ksrc, ktrg, mask, wq, tidx,
                                                  minfoF, minfoI, out);
  phaseB<<<NBLK, 256, 0, stream>>>(ft, wq, tidx, partM, partS, trgl);
  reduceFinal<<<BB * NN / 256, 256, 0, stream>>>(partM, partS, trgl, mask,
                                                 minfoF, minfoI, out);
}